// Round 7
// baseline (48.284 us; speedup 1.0000x reference)
//
#include <hip/hip_runtime.h>

// Table-batched embedding bags: weights [T*E, D=64] f32, indices [N] local,
// offsets [T*B+1] ragged bags (segment s = t*B + b), out [B, T, D] f32.
//
// One wave per bag. Lane=(r,c): r=lane>>4 row-slot, c=lane&15 float4 chunk.
// Each 64-row iteration: slot r covers rows {i+8r..i+8r+7} and
// {i+32+8r..i+32+8r+7}. Indices come from FOUR aligned int4 broadcast loads
// (same addr across the slot's 16 lanes -> one line lookup each, no DS ops),
// then all 16 gathers issue together (256 B/lane in flight). Rows outside
// [start,end) are exec-masked from gather and accumulate; their index values
// belong to neighboring bags so addresses stay in-bounds. R5's bug (i+=64
// stride covering only 32 rows) fixed by the explicit second half.

__global__ __launch_bounds__(256) void emb_bags_kernel(
    const float* __restrict__ weights,
    const int*   __restrict__ table_offsets,
    const int*   __restrict__ indices,
    const int*   __restrict__ offsets,
    float*       __restrict__ out,
    int N, int TB, int B, int T)
{
    const int wave = (blockIdx.x * blockDim.x + threadIdx.x) >> 6;
    if (wave >= TB) return;
    const int lane = threadIdx.x & 63;
    const int c = lane & 15;   // float4 chunk within row
    const int r = lane >> 4;   // row slot 0..3

    const int t = wave / B;
    const int b = wave - t * B;
    const int start = offsets[wave];
    const int end   = offsets[wave + 1];
    const long long tbase = table_offsets[t];

    const float4* __restrict__ w4 = (const float4*)weights;

    float4 a0 = make_float4(0.f, 0.f, 0.f, 0.f);
    float4 a1 = a0;

    const int astart = start & ~7;       // 32B-aligned index base

    for (int i = astart; i < end; i += 64) {
        const int base0 = i + (r << 3);        // slot's rows, first half
        const int base1 = base0 + 32;          // slot's rows, second half

        // ---- all 16 indices first (4 aligned int4 broadcast loads) ----
        int id[16];
        if (i + 64 <= N) {
            const int4 q0 = *(const int4*)(indices + base0);
            const int4 q1 = *(const int4*)(indices + base0 + 4);
            const int4 q2 = *(const int4*)(indices + base1);
            const int4 q3 = *(const int4*)(indices + base1 + 4);
            id[0]=q0.x; id[1]=q0.y; id[2]=q0.z;  id[3]=q0.w;
            id[4]=q1.x; id[5]=q1.y; id[6]=q1.z;  id[7]=q1.w;
            id[8]=q2.x; id[9]=q2.y; id[10]=q2.z; id[11]=q2.w;
            id[12]=q3.x; id[13]=q3.y; id[14]=q3.z; id[15]=q3.w;
        } else {                               // rare tail at end of N
            #pragma unroll
            for (int k = 0; k < 16; ++k) {
                const int p = (k < 8 ? base0 + k : base1 + k - 8);
                id[k] = indices[p < N ? p : (N - 1)];
            }
        }

        // ---- 16 independent gathers, exec-masked to this bag's rows ----
        float4 v[16];
        #pragma unroll
        for (int k = 0; k < 16; ++k) {
            const int p = (k < 8 ? base0 + k : base1 + k - 8);
            v[k] = make_float4(0.f, 0.f, 0.f, 0.f);
            if (p >= start && p < end)
                v[k] = w4[((size_t)(tbase + id[k]) << 4) + c];
        }

        #pragma unroll
        for (int k = 0; k < 16; k += 2) {
            a0.x += v[k].x;     a0.y += v[k].y;
            a0.z += v[k].z;     a0.w += v[k].w;
            a1.x += v[k + 1].x; a1.y += v[k + 1].y;
            a1.z += v[k + 1].z; a1.w += v[k + 1].w;
        }
    }

    float4 a;
    a.x = a0.x + a1.x;
    a.y = a0.y + a1.y;
    a.z = a0.z + a1.z;
    a.w = a0.w + a1.w;

    // reduce across the 4 row-slots (lane bits 4 and 5)
    #pragma unroll
    for (int m = 16; m < 64; m <<= 1) {
        a.x += __shfl_xor(a.x, m, 64);
        a.y += __shfl_xor(a.y, m, 64);
        a.z += __shfl_xor(a.z, m, 64);
        a.w += __shfl_xor(a.w, m, 64);
    }

    if (r == 0) {
        float4* o4 = (float4*)out;
        o4[(((size_t)b * T + t) << 4) + c] = a;  // out[b, t, c*4 .. c*4+3]
    }
}

extern "C" void kernel_launch(void* const* d_in, const int* in_sizes, int n_in,
                              void* d_out, int out_size, void* d_ws, size_t ws_size,
                              hipStream_t stream) {
    const float* weights       = (const float*)d_in[0];
    const int*   table_offsets = (const int*)d_in[1];
    const int*   indices       = (const int*)d_in[2];
    const int*   offsets       = (const int*)d_in[3];
    float*       out           = (float*)d_out;

    const int T  = in_sizes[1];          // 8
    const int TB = in_sizes[3] - 1;      // T*B
    const int B  = TB / T;               // 2048
    const int N  = in_sizes[2];          // total index rows

    const int threads = 256;             // 4 waves/block
    const int blocks  = (TB * 64 + threads - 1) / threads;
    emb_bags_kernel<<<blocks, threads, 0, stream>>>(
        weights, table_offsets, indices, offsets, out, N, TB, B, T);
}